// Round 1
// 546.247 us; speedup vs baseline: 1.1680x; 1.1680x over previous
//
#include <hip/hip_runtime.h>
#include <hip/hip_bf16.h>
#include <cstddef>
#include <cstdint>

#define LN_EPS 1e-5f

// Problem dims (fixed by the reference)
#define B_DIM 8192
#define D_DIM 4096
#define H_DIM 2048
#define K_DIM 512

typedef __bf16 bf16x8_t __attribute__((ext_vector_type(8)));
typedef float f32x4_t __attribute__((ext_vector_type(4)));

// ---------------------------------------------------------------------------
// async global->LDS, 16B per lane. LDS dest = wave-uniform base + lane*16.
// ---------------------------------------------------------------------------
__device__ __forceinline__ void gl2lds16(const __hip_bfloat16* g,
                                         __hip_bfloat16* l) {
  __builtin_amdgcn_global_load_lds(
      (const __attribute__((address_space(1))) uint32_t*)g,
      (__attribute__((address_space(3))) uint32_t*)l, 16, 0, 0);
}

// ---------------------------------------------------------------------------
// f32 -> bf16 pre-convert passes (memory-bound, 8 elems/thread)
// ---------------------------------------------------------------------------
__global__ __launch_bounds__(256) void conv_x_kernel(
    const float* __restrict__ x, const float* __restrict__ cmean,
    __hip_bfloat16* __restrict__ out) {
  const long i = (((long)blockIdx.x << 8) + threadIdx.x) << 3;
  const int col = (int)(i & (D_DIM - 1));
  const float4 a = *(const float4*)(x + i);
  const float4 b = *(const float4*)(x + i + 4);
  const float4 ma = *(const float4*)(cmean + col);
  const float4 mb = *(const float4*)(cmean + col + 4);
  union { __hip_bfloat16 h[8]; uint4 u; } pk;
  pk.h[0] = __float2bfloat16(a.x - ma.x);
  pk.h[1] = __float2bfloat16(a.y - ma.y);
  pk.h[2] = __float2bfloat16(a.z - ma.z);
  pk.h[3] = __float2bfloat16(a.w - ma.w);
  pk.h[4] = __float2bfloat16(b.x - mb.x);
  pk.h[5] = __float2bfloat16(b.y - mb.y);
  pk.h[6] = __float2bfloat16(b.z - mb.z);
  pk.h[7] = __float2bfloat16(b.w - mb.w);
  *(uint4*)(out + i) = pk.u;
}

// One launch converting W1 (4096 blocks), W2 (512), beta (1024). 2048 f32/blk.
__global__ __launch_bounds__(256) void conv_w3_kernel(
    const float* __restrict__ W1, const float* __restrict__ W2,
    const float* __restrict__ beta, __hip_bfloat16* __restrict__ W1b,
    __hip_bfloat16* __restrict__ W2b, __hip_bfloat16* __restrict__ betab) {
  const int blk = blockIdx.x;
  const float* src;
  __hip_bfloat16* dst;
  long base;
  if (blk < 4096) {
    src = W1; dst = W1b; base = blk;
  } else if (blk < 4608) {
    src = W2; dst = W2b; base = blk - 4096;
  } else {
    src = beta; dst = betab; base = blk - 4608;
  }
  const long i = ((base << 8) + threadIdx.x) << 3;
  const float4 a = *(const float4*)(src + i);
  const float4 b = *(const float4*)(src + i + 4);
  union { __hip_bfloat16 h[8]; uint4 u; } pk;
  pk.h[0] = __float2bfloat16(a.x);
  pk.h[1] = __float2bfloat16(a.y);
  pk.h[2] = __float2bfloat16(a.z);
  pk.h[3] = __float2bfloat16(a.w);
  pk.h[4] = __float2bfloat16(b.x);
  pk.h[5] = __float2bfloat16(b.y);
  pk.h[6] = __float2bfloat16(b.z);
  pk.h[7] = __float2bfloat16(b.w);
  *(uint4*)(dst + i) = pk.u;
}

// ---------------------------------------------------------------------------
// OLD m97-style 128x128 NT GEMM, kept for fc2 only (N=512: 256 blocks at
// 128-tile vs a starving 64 blocks at 256-tile).
// ---------------------------------------------------------------------------
template <int EPI>
__global__ __launch_bounds__(256) void gemm_bt(
    const __hip_bfloat16* __restrict__ A, int lda,
    const __hip_bfloat16* __restrict__ Bm, int ldb,
    const float* __restrict__ bias, float* __restrict__ C0, int ldc,
    float* __restrict__ C2, float* __restrict__ C3,
    __hip_bfloat16* __restrict__ Cb, int Kd) {
  __shared__ __hip_bfloat16 lA[128 * 32];
  __shared__ __hip_bfloat16 lB[128 * 32];

  const int t = threadIdx.x;
  const int lane = t & 63;
  const int wv = t >> 6;
  const int wm = (wv >> 1) * 64;
  const int wn = (wv & 1) * 64;
  const int fr = lane & 15;
  const int ko = lane >> 4;
  const int kos = (ko ^ ((fr >> 1) & 3)) * 8;

  const long rowA = (long)blockIdx.y * 128;
  const long rowB = (long)blockIdx.x * 128;

  const int ci = wv * 128 + lane;
  const int srow = ci >> 2;
  const int scol = (((ci & 3) ^ ((ci >> 3) & 3))) * 8;
  const __hip_bfloat16* pA0 = A + (rowA + srow) * (long)lda + scol;
  const __hip_bfloat16* pA1 = pA0 + 16L * lda;
  const __hip_bfloat16* pB0 = Bm + (rowB + srow) * (long)ldb + scol;
  const __hip_bfloat16* pB1 = pB0 + 16L * ldb;
  __hip_bfloat16* lA0 = lA + wv * 128 * 8;
  __hip_bfloat16* lA1 = lA0 + 64 * 8;
  __hip_bfloat16* lB0 = lB + wv * 128 * 8;
  __hip_bfloat16* lB1 = lB0 + 64 * 8;

  f32x4_t acc[4][4];
  const f32x4_t zero = {0.f, 0.f, 0.f, 0.f};
#pragma unroll
  for (int mi = 0; mi < 4; ++mi)
#pragma unroll
    for (int ni = 0; ni < 4; ++ni) acc[mi][ni] = zero;

  for (int k0 = 0; k0 < Kd; k0 += 32) {
    gl2lds16(pA0 + k0, lA0);
    gl2lds16(pA1 + k0, lA1);
    gl2lds16(pB0 + k0, lB0);
    gl2lds16(pB1 + k0, lB1);
    __syncthreads();

    bf16x8_t af[4], bfv[4];
#pragma unroll
    for (int mi = 0; mi < 4; ++mi)
      af[mi] = *(const bf16x8_t*)&lA[(wm + mi * 16 + fr) * 32 + kos];
#pragma unroll
    for (int ni = 0; ni < 4; ++ni)
      bfv[ni] = *(const bf16x8_t*)&lB[(wn + ni * 16 + fr) * 32 + kos];
#pragma unroll
    for (int mi = 0; mi < 4; ++mi)
#pragma unroll
      for (int ni = 0; ni < 4; ++ni)
        acc[mi][ni] = __builtin_amdgcn_mfma_f32_16x16x32_bf16(
            af[mi], bfv[ni], acc[mi][ni], 0, 0, 0);
    __syncthreads();
  }

  const long cRow0 = rowA + wm;
  const int cCol0 = (int)rowB + wn;
#pragma unroll
  for (int mi = 0; mi < 4; ++mi) {
#pragma unroll
    for (int ni = 0; ni < 4; ++ni) {
      f32x4_t a = acc[mi][ni];
      int col = cCol0 + ni * 16 + fr;
#pragma unroll
      for (int r = 0; r < 4; ++r) {
        long row = cRow0 + mi * 16 + ko * 4 + r;
        float val = a[r];
        if constexpr (EPI == 0) {
          val += bias[col];
          C0[row * (long)ldc + col] = val;
        } else if constexpr (EPI == 1) {
          val += bias[col];
          C0[row * (long)ldc + col] = val;
          C2[row * (long)ldc + col] = val;
          C3[row * (long)ldc + col] = val;
          Cb[row * (long)ldc + col] = __float2bfloat16(val);
        } else {
          val = 1.f / (1.f + __expf(-val));
          C0[row * (long)ldc + col] = val;
        }
      }
    }
  }
}

// ---------------------------------------------------------------------------
// NEW 256x256 NT GEMM (T2+T3+T4+T5): C = A * B^T (+epilogue).
// 8 waves (2M x 4N), per-wave 128x64 output = acc[8][4] 16x16 frags.
// BK=32, 3-slot LDS ring (96 KB), depth-2 prefetch: while computing K-tile t
// from slot t%3, the 4 global_load_lds of tile t+2 are issued into slot
// (t+2)%3. Group boundary = s_waitcnt vmcnt(4) (tile t+2's loads STAY IN
// FLIGHT across the raw s_barrier — never vmcnt(0) in steady state).
// Race-freedom: slot s is rewritten only 2 groups after its last read, and
// every wave lgkm-drains its reads (before its MFMAs) before reaching the
// boundary barrier, so post-barrier DMA writes cannot land under a reader.
// 32 MFMA per barrier (AITER ratio) vs 16-per-2-drained-barriers in gemm_bt.
//
// LDS chunk swizzle identical to gemm_bt (verified conflict-free, 0
// SQ_LDS_BANK_CONFLICT): logical (row,kq) chunk at phys row*4+(kq^((row>>1)&3));
// inverse folded into the per-lane staging SOURCE index; fragment reads use
// kos = (ko ^ ((fr>>1)&3))*8 (row base is a multiple of 16 so only fr feeds
// the XOR).  EPI 0: +bias (fc1). EPI 2: sigmoid (decode).
// ---------------------------------------------------------------------------
template <int EPI>
__global__ __launch_bounds__(512, 2) void gemm256_bt(
    const __hip_bfloat16* __restrict__ A, int lda,
    const __hip_bfloat16* __restrict__ Bm, int ldb,
    const float* __restrict__ bias, float* __restrict__ C0, int ldc, int Kd) {
  constexpr int SLOT = 16384;  // bf16 elems per ring slot: A 8192 + B 8192
  __shared__ __hip_bfloat16 lds[3 * SLOT];  // 96 KB

  const int t_ = threadIdx.x;
  const int lane = t_ & 63;
  const int wv = t_ >> 6;
  const int wr = wv >> 2;  // M half (0..1) -> rows wr*128..wr*128+127
  const int wc = wv & 3;   // N quarter (0..3) -> cols wc*64..wc*64+63
  const int fr = lane & 15;
  const int ko = lane >> 4;
  const int kos = (ko ^ ((fr >> 1) & 3)) * 8;

  const long rowA = (long)blockIdx.y * 256;
  const long rowB = (long)blockIdx.x * 256;

  // Staging geometry: 1024 16B-chunks per matrix per slot; wave wv fills
  // chunks [wv*64, wv*64+64) (rows 0..127) and +512 (rows 128..255), one
  // global_load_lds each. Source index carries the swizzle inverse; +512
  // doesn't disturb chunk bits 0..4 so the same scol applies to both halves.
  const int ci = (wv << 6) + lane;  // 0..511
  const int srow = ci >> 2;         // 0..127
  const int scol = ((ci & 3) ^ ((ci >> 3) & 3)) << 3;
  const __hip_bfloat16* pA0 = A + (rowA + srow) * (long)lda + scol;
  const __hip_bfloat16* pA1 = pA0 + 128L * lda;
  const __hip_bfloat16* pB0 = Bm + (rowB + srow) * (long)ldb + scol;
  const __hip_bfloat16* pB1 = pB0 + 128L * ldb;

  f32x4_t acc[8][4];
  const f32x4_t zero = {0.f, 0.f, 0.f, 0.f};
#pragma unroll
  for (int mi = 0; mi < 8; ++mi)
#pragma unroll
    for (int ni = 0; ni < 4; ++ni) acc[mi][ni] = zero;

  const int NT = Kd >> 5;  // 32-wide K-tiles

  // Prologue: stage tiles 0 and 1 into slots 0 and 1.
  {
    __hip_bfloat16* a0 = lds + wv * 512;
    gl2lds16(pA0, a0);
    gl2lds16(pA1, a0 + 4096);
    __hip_bfloat16* b0 = lds + 8192 + wv * 512;
    gl2lds16(pB0, b0);
    gl2lds16(pB1, b0 + 4096);
  }
  if (NT > 1) {
    __hip_bfloat16* a1 = lds + SLOT + wv * 512;
    gl2lds16(pA0 + 32, a1);
    gl2lds16(pA1 + 32, a1 + 4096);
    __hip_bfloat16* b1 = lds + SLOT + 8192 + wv * 512;
    gl2lds16(pB0 + 32, b1);
    gl2lds16(pB1 + 32, b1 + 4096);
    asm volatile("s_waitcnt vmcnt(4)" ::: "memory");  // tile0 landed
  } else {
    asm volatile("s_waitcnt vmcnt(0)" ::: "memory");
  }
  __builtin_amdgcn_s_barrier();
  __builtin_amdgcn_sched_barrier(0);

  for (int t = 0; t < NT; ++t) {
    const int slot = t % 3;
    const int nslot = (t + 2) % 3;
    const __hip_bfloat16* sA = lds + slot * SLOT;
    const __hip_bfloat16* sB = sA + 8192;
    const int kk = (t + 2) << 5;
    const bool pf = (t + 2) < NT;

    // ---- phase A: m-frags 0..3 (wave rows +0..63) x all 4 n-frags ----
    bf16x8_t af[4], bfv[4];
#pragma unroll
    for (int mi = 0; mi < 4; ++mi)
      af[mi] = *(const bf16x8_t*)&sA[(wr * 128 + mi * 16 + fr) * 32 + kos];
#pragma unroll
    for (int ni = 0; ni < 4; ++ni)
      bfv[ni] = *(const bf16x8_t*)&sB[(wc * 64 + ni * 16 + fr) * 32 + kos];
    if (pf) {  // issue A-halves of tile t+2
      __hip_bfloat16* la = lds + nslot * SLOT + wv * 512;
      gl2lds16(pA0 + kk, la);
      gl2lds16(pA1 + kk, la + 4096);
    }
    __builtin_amdgcn_s_setprio(1);
#pragma unroll
    for (int mi = 0; mi < 4; ++mi)
#pragma unroll
      for (int ni = 0; ni < 4; ++ni)
        acc[mi][ni] = __builtin_amdgcn_mfma_f32_16x16x32_bf16(
            af[mi], bfv[ni], acc[mi][ni], 0, 0, 0);
    __builtin_amdgcn_s_setprio(0);

    // ---- phase B: m-frags 4..7 (wave rows +64..127), B-frags reused ----
    bf16x8_t ag[4];
#pragma unroll
    for (int mi = 0; mi < 4; ++mi)
      ag[mi] =
          *(const bf16x8_t*)&sA[(wr * 128 + 64 + mi * 16 + fr) * 32 + kos];
    if (pf) {  // issue B-halves of tile t+2
      __hip_bfloat16* lb = lds + nslot * SLOT + 8192 + wv * 512;
      gl2lds16(pB0 + kk, lb);
      gl2lds16(pB1 + kk, lb + 4096);
    }
    __builtin_amdgcn_s_setprio(1);
#pragma unroll
    for (int mi = 0; mi < 4; ++mi)
#pragma unroll
      for (int ni = 0; ni < 4; ++ni)
        acc[4 + mi][ni] = __builtin_amdgcn_mfma_f32_16x16x32_bf16(
            ag[mi], bfv[ni], acc[4 + mi][ni], 0, 0, 0);
    __builtin_amdgcn_s_setprio(0);

    // ---- group boundary: tile t+1 must be resident; t+2 stays in flight ----
    if (t + 1 < NT) {
      if (pf)
        asm volatile("s_waitcnt vmcnt(4)" ::: "memory");
      else
        asm volatile("s_waitcnt vmcnt(0)" ::: "memory");  // tail only
      __builtin_amdgcn_s_barrier();
      __builtin_amdgcn_sched_barrier(0);
    }
  }

  // Epilogue. C/D layout: col = lane&15, row = (lane>>4)*4 + reg.
  const long cRow0 = rowA + wr * 128;
  const int cCol0 = (int)rowB + wc * 64;
#pragma unroll
  for (int mi = 0; mi < 8; ++mi) {
#pragma unroll
    for (int ni = 0; ni < 4; ++ni) {
      f32x4_t a = acc[mi][ni];
      const int col = cCol0 + ni * 16 + fr;
#pragma unroll
      for (int r = 0; r < 4; ++r) {
        const long row = cRow0 + mi * 16 + ko * 4 + r;
        float val = a[r];
        if constexpr (EPI == 0) {
          val += bias[col];
        } else {
          val = 1.f / (1.f + __expf(-val));
        }
        C0[row * (long)ldc + col] = val;
      }
    }
  }
}

// ---------------------------------------------------------------------------
// Row LayerNorm + ReLU over h [8192 x 2048] f32; writes bf16 h' IN PLACE
// (bf16 row stride 4096 elems = the f32 row byte size). Reads before writes.
// ---------------------------------------------------------------------------
__global__ __launch_bounds__(256) void ln_relu_kernel(
    void* hptr, const float* __restrict__ ln_w, const float* __restrict__ ln_b) {
  const int H = H_DIM;
  float* h = (float*)hptr;
  __hip_bfloat16* hb = (__hip_bfloat16*)hptr;

  const long row = blockIdx.x;
  const int t = threadIdx.x;
  const int lane = t & 63;
  const int wv = t >> 6;
  const float* hr = h + row * H;

  float v[8];
#pragma unroll
  for (int i = 0; i < 8; ++i) v[i] = hr[t + i * 256];

  __shared__ float red[8];

  float s = 0.f;
#pragma unroll
  for (int i = 0; i < 8; ++i) s += v[i];
#pragma unroll
  for (int off = 32; off; off >>= 1) s += __shfl_down(s, off);
  if (lane == 0) red[wv] = s;
  __syncthreads();
  const float mu = (red[0] + red[1] + red[2] + red[3]) * (1.f / (float)H);

  float vs = 0.f;
#pragma unroll
  for (int i = 0; i < 8; ++i) {
    float d = v[i] - mu;
    vs += d * d;
  }
#pragma unroll
  for (int off = 32; off; off >>= 1) vs += __shfl_down(vs, off);
  if (lane == 0) red[4 + wv] = vs;
  __syncthreads();
  const float var = (red[4] + red[5] + red[6] + red[7]) * (1.f / (float)H);
  const float rs = rsqrtf(var + LN_EPS);

  __hip_bfloat16* hbr = hb + row * (long)D_DIM;
#pragma unroll
  for (int i = 0; i < 8; ++i) {
    int col = t + i * 256;
    float y = (v[i] - mu) * rs * ln_w[col] + ln_b[col];
    y = fmaxf(y, 0.f);
    hbr[col] = __float2bfloat16(y);
  }
}

// ---------------------------------------------------------------------------
extern "C" void kernel_launch(void* const* d_in, const int* in_sizes, int n_in,
                              void* d_out, int out_size, void* d_ws,
                              size_t ws_size, hipStream_t stream) {
  const float* x = (const float*)d_in[0];     // [8192,4096]
  const float* beta = (const float*)d_in[1];  // [4096,512]
  const float* cmean = (const float*)d_in[2]; // [4096]
  const float* W1 = (const float*)d_in[3];    // [2048,4096]
  const float* b1 = (const float*)d_in[4];    // [2048]
  const float* ln_w = (const float*)d_in[5];  // [2048]
  const float* ln_b = (const float*)d_in[6];  // [2048]
  const float* W2 = (const float*)d_in[7];    // [512,2048]
  const float* b2 = (const float*)d_in[8];    // [512]

  float* out = (float*)d_out;
  float* q0 = out;                          // [8192,512]
  float* xr = out + (size_t)B_DIM * K_DIM;  // [8192,4096] — 134 MB region
  float* q2 = xr + (size_t)B_DIM * D_DIM;   // [8192,512]
  float* q3 = q2 + (size_t)B_DIM * K_DIM;   // [8192,512]

  // Scratch inside d_out's xr region (dead until final decode GEMM):
  //   xb: bf16(x - cmean) [8192,4096] = 64 MB at xr+0
  //   h : f32 fc1 output  [8192,2048] = 64 MB at xr + 16.78M floats
  __hip_bfloat16* xb = (__hip_bfloat16*)xr;
  float* h = xr + (size_t)B_DIM * D_DIM / 2;
  __hip_bfloat16* hb = (__hip_bfloat16*)h;  // ln_relu writes bf16 in place

  // ws: bf16 weights + q bf16 (30 MB total; ws proven >= 64 MB)
  __hip_bfloat16* W1b = (__hip_bfloat16*)d_ws;          // 2048*4096
  __hip_bfloat16* W2b = W1b + (size_t)H_DIM * D_DIM;    // 512*2048
  __hip_bfloat16* betab = W2b + (size_t)K_DIM * H_DIM;  // 4096*512
  __hip_bfloat16* qb = betab + (size_t)D_DIM * K_DIM;   // 8192*512

  dim3 blk(256, 1, 1);
  dim3 blk512(512, 1, 1);

  // Pre-convert to bf16 (memory-bound, 2 launches)
  hipLaunchKernelGGL(conv_x_kernel, dim3((B_DIM * (size_t)D_DIM) / 2048), blk,
                     0, stream, x, cmean, xb);
  hipLaunchKernelGGL(conv_w3_kernel, dim3(4096 + 512 + 1024), blk, 0, stream,
                     W1, W2, beta, W1b, W2b, betab);

  // fc1: h = xb @ W1b^T + b1   [M=8192, N=2048, Kd=4096] — 256^2 pipelined
  hipLaunchKernelGGL((gemm256_bt<0>), dim3(H_DIM / 256, B_DIM / 256), blk512,
                     0, stream, xb, D_DIM, W1b, D_DIM, b1, h, H_DIM, D_DIM);

  // LayerNorm + ReLU -> bf16 h' in place (row stride 4096)
  hipLaunchKernelGGL(ln_relu_kernel, dim3(B_DIM), blk, 0, stream, (void*)h,
                     ln_w, ln_b);

  // fc2: q = h' @ W2b^T + b2   [M=8192, N=512, Kd=2048] -> q0,q2,q3 + qb bf16
  // (kept on 128^2 kernel: 256 blocks vs 64 at 256-tile)
  hipLaunchKernelGGL((gemm_bt<1>), dim3(K_DIM / 128, B_DIM / 128), blk, 0,
                     stream, hb, D_DIM, W2b, H_DIM, b2, q0, K_DIM, q2, q3, qb,
                     H_DIM);

  // decode: x_recon = sigmoid(qb @ betab^T)  [M=8192, N=4096, Kd=512] — 256^2
  hipLaunchKernelGGL((gemm256_bt<2>), dim3(D_DIM / 256, B_DIM / 256), blk512,
                     0, stream, qb, K_DIM, betab, K_DIM, (const float*)nullptr,
                     xr, D_DIM, K_DIM);
}

// Round 2
// 531.958 us; speedup vs baseline: 1.1994x; 1.0269x over previous
//
#include <hip/hip_runtime.h>
#include <hip/hip_bf16.h>
#include <cstddef>
#include <cstdint>

#define LN_EPS 1e-5f

// Problem dims (fixed by the reference)
#define B_DIM 8192
#define D_DIM 4096
#define H_DIM 2048
#define K_DIM 512

typedef __bf16 bf16x8_t __attribute__((ext_vector_type(8)));
typedef float f32x4_t __attribute__((ext_vector_type(4)));

// ---------------------------------------------------------------------------
// async global->LDS, 16B per lane. LDS dest = wave-uniform base + lane*16.
// ---------------------------------------------------------------------------
__device__ __forceinline__ void gl2lds16(const __hip_bfloat16* g,
                                         __hip_bfloat16* l) {
  __builtin_amdgcn_global_load_lds(
      (const __attribute__((address_space(1))) uint32_t*)g,
      (__attribute__((address_space(3))) uint32_t*)l, 16, 0, 0);
}

// ---------------------------------------------------------------------------
// f32 -> bf16 pre-convert passes (memory-bound, 8 elems/thread)
// ---------------------------------------------------------------------------
__global__ __launch_bounds__(256) void conv_x_kernel(
    const float* __restrict__ x, const float* __restrict__ cmean,
    __hip_bfloat16* __restrict__ out) {
  const long i = (((long)blockIdx.x << 8) + threadIdx.x) << 3;
  const int col = (int)(i & (D_DIM - 1));
  const float4 a = *(const float4*)(x + i);
  const float4 b = *(const float4*)(x + i + 4);
  const float4 ma = *(const float4*)(cmean + col);
  const float4 mb = *(const float4*)(cmean + col + 4);
  union { __hip_bfloat16 h[8]; uint4 u; } pk;
  pk.h[0] = __float2bfloat16(a.x - ma.x);
  pk.h[1] = __float2bfloat16(a.y - ma.y);
  pk.h[2] = __float2bfloat16(a.z - ma.z);
  pk.h[3] = __float2bfloat16(a.w - ma.w);
  pk.h[4] = __float2bfloat16(b.x - mb.x);
  pk.h[5] = __float2bfloat16(b.y - mb.y);
  pk.h[6] = __float2bfloat16(b.z - mb.z);
  pk.h[7] = __float2bfloat16(b.w - mb.w);
  *(uint4*)(out + i) = pk.u;
}

// One launch converting W1 (4096 blocks), W2 (512), beta (1024). 2048 f32/blk.
__global__ __launch_bounds__(256) void conv_w3_kernel(
    const float* __restrict__ W1, const float* __restrict__ W2,
    const float* __restrict__ beta, __hip_bfloat16* __restrict__ W1b,
    __hip_bfloat16* __restrict__ W2b, __hip_bfloat16* __restrict__ betab) {
  const int blk = blockIdx.x;
  const float* src;
  __hip_bfloat16* dst;
  long base;
  if (blk < 4096) {
    src = W1; dst = W1b; base = blk;
  } else if (blk < 4608) {
    src = W2; dst = W2b; base = blk - 4096;
  } else {
    src = beta; dst = betab; base = blk - 4608;
  }
  const long i = ((base << 8) + threadIdx.x) << 3;
  const float4 a = *(const float4*)(src + i);
  const float4 b = *(const float4*)(src + i + 4);
  union { __hip_bfloat16 h[8]; uint4 u; } pk;
  pk.h[0] = __float2bfloat16(a.x);
  pk.h[1] = __float2bfloat16(a.y);
  pk.h[2] = __float2bfloat16(a.z);
  pk.h[3] = __float2bfloat16(a.w);
  pk.h[4] = __float2bfloat16(b.x);
  pk.h[5] = __float2bfloat16(b.y);
  pk.h[6] = __float2bfloat16(b.z);
  pk.h[7] = __float2bfloat16(b.w);
  *(uint4*)(dst + i) = pk.u;
}

// ---------------------------------------------------------------------------
// m97-style 128x128 NT GEMM, kept for fc2 only (N=512). + T1 XCD swizzle.
// ---------------------------------------------------------------------------
template <int EPI>
__global__ __launch_bounds__(256) void gemm_bt(
    const __hip_bfloat16* __restrict__ A, int lda,
    const __hip_bfloat16* __restrict__ Bm, int ldb,
    const float* __restrict__ bias, float* __restrict__ C0, int ldc,
    float* __restrict__ C2, float* __restrict__ C3,
    __hip_bfloat16* __restrict__ Cb, int Kd) {
  __shared__ __hip_bfloat16 lA[128 * 32];
  __shared__ __hip_bfloat16 lB[128 * 32];

  const int t = threadIdx.x;
  const int lane = t & 63;
  const int wv = t >> 6;
  const int wm = (wv >> 1) * 64;
  const int wn = (wv & 1) * 64;
  const int fr = lane & 15;
  const int ko = lane >> 4;
  const int kos = (ko ^ ((fr >> 1) & 3)) * 8;

  // XCD-aware bijective swizzle (grid 4x64 = 256 wgs, %8==0)
  const int gx = gridDim.x;
  const int nwg = gx * gridDim.y;
  const int f = blockIdx.y * gx + blockIdx.x;
  const int w = (f & 7) * (nwg >> 3) + (f >> 3);
  const int bx = w % gx;
  const int by = w / gx;

  const long rowA = (long)by * 128;
  const long rowB = (long)bx * 128;

  const int ci = wv * 128 + lane;
  const int srow = ci >> 2;
  const int scol = (((ci & 3) ^ ((ci >> 3) & 3))) * 8;
  const __hip_bfloat16* pA0 = A + (rowA + srow) * (long)lda + scol;
  const __hip_bfloat16* pA1 = pA0 + 16L * lda;
  const __hip_bfloat16* pB0 = Bm + (rowB + srow) * (long)ldb + scol;
  const __hip_bfloat16* pB1 = pB0 + 16L * ldb;
  __hip_bfloat16* lA0 = lA + wv * 128 * 8;
  __hip_bfloat16* lA1 = lA0 + 64 * 8;
  __hip_bfloat16* lB0 = lB + wv * 128 * 8;
  __hip_bfloat16* lB1 = lB0 + 64 * 8;

  f32x4_t acc[4][4];
  const f32x4_t zero = {0.f, 0.f, 0.f, 0.f};
#pragma unroll
  for (int mi = 0; mi < 4; ++mi)
#pragma unroll
    for (int ni = 0; ni < 4; ++ni) acc[mi][ni] = zero;

  for (int k0 = 0; k0 < Kd; k0 += 32) {
    gl2lds16(pA0 + k0, lA0);
    gl2lds16(pA1 + k0, lA1);
    gl2lds16(pB0 + k0, lB0);
    gl2lds16(pB1 + k0, lB1);
    __syncthreads();

    bf16x8_t af[4], bfv[4];
#pragma unroll
    for (int mi = 0; mi < 4; ++mi)
      af[mi] = *(const bf16x8_t*)&lA[(wm + mi * 16 + fr) * 32 + kos];
#pragma unroll
    for (int ni = 0; ni < 4; ++ni)
      bfv[ni] = *(const bf16x8_t*)&lB[(wn + ni * 16 + fr) * 32 + kos];
#pragma unroll
    for (int mi = 0; mi < 4; ++mi)
#pragma unroll
      for (int ni = 0; ni < 4; ++ni)
        acc[mi][ni] = __builtin_amdgcn_mfma_f32_16x16x32_bf16(
            af[mi], bfv[ni], acc[mi][ni], 0, 0, 0);
    __syncthreads();
  }

  const long cRow0 = rowA + wm;
  const int cCol0 = (int)rowB + wn;
#pragma unroll
  for (int mi = 0; mi < 4; ++mi) {
#pragma unroll
    for (int ni = 0; ni < 4; ++ni) {
      f32x4_t a = acc[mi][ni];
      int col = cCol0 + ni * 16 + fr;
#pragma unroll
      for (int r = 0; r < 4; ++r) {
        long row = cRow0 + mi * 16 + ko * 4 + r;
        float val = a[r];
        if constexpr (EPI == 0) {
          val += bias[col];
          C0[row * (long)ldc + col] = val;
        } else if constexpr (EPI == 1) {
          val += bias[col];
          C0[row * (long)ldc + col] = val;
          C2[row * (long)ldc + col] = val;
          C3[row * (long)ldc + col] = val;
          Cb[row * (long)ldc + col] = __float2bfloat16(val);
        } else {
          val = 1.f / (1.f + __expf(-val));
          C0[row * (long)ldc + col] = val;
        }
      }
    }
  }
}

// ---------------------------------------------------------------------------
// 256x256 8-PHASE NT GEMM (T1+T2+T3+T4+T5): C = A*B^T (+epilogue).
// 8 waves (2M x 4N), per-wave 128x64 = acc[8][4]. BK=64, 2 K-tiles/iter.
// LDS 128KB: 2 bufs x {A0,A1,B0,B1} half-tile slots (128 rows x 64k = 16KB).
// Even tiles -> buf0, odd -> buf1.
//
// Per-tile read phases (quadrant (mh,nh)): P(0,0)=12 ds_reads (A-low 8 + B-lo
// 4), P(0,1)=4 (B-hi), P(1,0)=8 (A-hi), P(1,1)=0. Each wave reads only its
// own A-half (wr) and B-half (wc>>1); slot last-reads: A-halves at P3/P7,
// B-halves at P2/P6.
//
// Staging: one half-tile (2 gl2lds) per phase, each placed >=1 phase after
// the slot's last read (prev phase's lgkmcnt(0) + end-barrier orders it):
//   p1: buf1.A0 (tile 2i+1)   p5: buf0.A0 (tile 2i+2)
//   p2: buf1.A1 (tile 2i+1)   p6: buf0.A1 (tile 2i+2)
//   p3: buf0.B0 (tile 2i+2)   p7: buf1.B0 (tile 2i+3)
//   p4: buf0.B1 (tile 2i+2)   p8: buf1.B1 (tile 2i+3)
// Counted vmcnt(4) ONLY at p4 and p8 (after the MFMA cluster, before the end
// barrier): the 4 newest loads (= 2 half-tiles) stay in flight across the
// barrier; everything older is guaranteed landed for the next 4 phases'
// reads. Drains to 0 only in the last iteration (p4, no-prefetch path).
//
// LDS swizzle (T2, proven 0-conflict scheme extended to 8 kq-groups): logical
// 16B chunk (row, kq) lives at phys row*8 + (kq ^ ((row>>1)&7)). Inverse is
// folded into the gl2lds SOURCE index (linear LDS dest, rule 21). Fragment
// reads: chunk = ((kh*4+ko) ^ (fr>>1)) -> 8 positions x 2 lanes = 2-way
// aliasing (free, m136).
// ---------------------------------------------------------------------------
template <int EPI>
__global__ __launch_bounds__(512, 2) void gemm256_8p(
    const __hip_bfloat16* __restrict__ A, int lda,
    const __hip_bfloat16* __restrict__ Bm, int ldb,
    const float* __restrict__ bias, float* __restrict__ C0, int ldc, int Kd) {
  __shared__ __hip_bfloat16 lds[65536];  // 128 KB

  const int t_ = threadIdx.x;
  const int lane = t_ & 63;
  const int wv = t_ >> 6;
  const int wr = wv >> 2;  // M half (0/1)
  const int wc = wv & 3;   // N quarter (0..3)
  const int fr = lane & 15;
  const int ko = lane >> 4;

  // T1: XCD-aware bijective swizzle (all our grids have nwg % 8 == 0)
  const int gx = gridDim.x;
  const int nwg = gx * gridDim.y;
  const int f = blockIdx.y * gx + blockIdx.x;
  const int w = (f & 7) * (nwg >> 3) + (f >> 3);
  const int bx = w % gx;
  const int by = w / gx;

  const long rowA = (long)by * 256;
  const long rowB = (long)bx * 256;

  // Staging source (per thread): phys chunk p1 = wv*64+lane covers local rows
  // 0..63 of a half-tile (8 chunks/row); second call = rows 64..127, same kq.
  const int p1 = (wv << 6) + lane;
  const int row1 = p1 >> 3;
  const int kq1 = (p1 & 7) ^ ((p1 >> 4) & 7);
  const __hip_bfloat16* sA0 = A + (rowA + row1) * (long)lda + kq1 * 8;
  const __hip_bfloat16* sA1 = A + (rowA + 128 + row1) * (long)lda + kq1 * 8;
  const __hip_bfloat16* sB0 = Bm + (rowB + row1) * (long)ldb + kq1 * 8;
  const __hip_bfloat16* sB1 = Bm + (rowB + 128 + row1) * (long)ldb + kq1 * 8;
  const long stepA = 64L * lda;
  const long stepB = 64L * ldb;

  // stage one half-tile: slotElem in {0,8192,16384,24576} (+32768 for buf1)
  auto STG = [&](const __hip_bfloat16* src, long step, int slotElem, int kofs) {
    __hip_bfloat16* d = lds + slotElem + wv * 512;
    gl2lds16(src + kofs, d);
    gl2lds16(src + step + kofs, d + 4096);
  };

  // fragment-read constants
  const int aSlotOff = wr * 8192;                 // within-buf A slot
  const int bSlotOff = 16384 + (wc >> 1) * 8192;  // within-buf B slot
  const int lcB = (wc & 1) * 64;                  // local col base in B slot
  const int ck0 = (ko ^ (fr >> 1)) * 8;           // kh=0 chunk offset (elems)
  const int ck1 = ((4 + ko) ^ (fr >> 1)) * 8;     // kh=1

  auto LDA4 = [&](bf16x8_t(&dst)[4][2], int base, int rbase) {
#pragma unroll
    for (int mi = 0; mi < 4; ++mi) {
      const int ro = base + (rbase + mi * 16 + fr) * 64;
      dst[mi][0] = *(const bf16x8_t*)&lds[ro + ck0];
      dst[mi][1] = *(const bf16x8_t*)&lds[ro + ck1];
    }
  };
  auto LDB2 = [&](bf16x8_t(&dst)[2][2], int base, int cbase) {
#pragma unroll
    for (int ni = 0; ni < 2; ++ni) {
      const int co = base + (cbase + ni * 16 + fr) * 64;
      dst[ni][0] = *(const bf16x8_t*)&lds[co + ck0];
      dst[ni][1] = *(const bf16x8_t*)&lds[co + ck1];
    }
  };

  f32x4_t acc[8][4];
  const f32x4_t zero = {0.f, 0.f, 0.f, 0.f};
#pragma unroll
  for (int a = 0; a < 8; ++a)
#pragma unroll
    for (int b = 0; b < 4; ++b) acc[a][b] = zero;

  auto MMA16 = [&](int amh, int anh, bf16x8_t(&aa)[4][2], bf16x8_t(&bb)[2][2]) {
    __builtin_amdgcn_s_setprio(1);
#pragma unroll
    for (int mi = 0; mi < 4; ++mi)
#pragma unroll
      for (int ni = 0; ni < 2; ++ni)
#pragma unroll
        for (int kh = 0; kh < 2; ++kh)
          acc[amh * 4 + mi][anh * 2 + ni] =
              __builtin_amdgcn_mfma_f32_16x16x32_bf16(
                  aa[mi][kh], bb[ni][kh], acc[amh * 4 + mi][anh * 2 + ni], 0,
                  0, 0);
    __builtin_amdgcn_s_setprio(0);
  };

#define BAR __builtin_amdgcn_s_barrier()
#define LGKM0                                          \
  {                                                    \
    asm volatile("s_waitcnt lgkmcnt(0)" ::: "memory"); \
    __builtin_amdgcn_sched_barrier(0);                 \
  }

  // Prologue: tile0 -> buf0 (4 slots), tile1 B-halves -> buf1. 12 loads;
  // vmcnt(4) leaves tile1's B in flight.
  STG(sA0, stepA, 0, 0);
  STG(sA1, stepA, 8192, 0);
  STG(sB0, stepB, 16384, 0);
  STG(sB1, stepB, 24576, 0);
  STG(sB0, stepB, 32768 + 16384, 64);
  STG(sB1, stepB, 32768 + 24576, 64);
  asm volatile("s_waitcnt vmcnt(4)" ::: "memory");
  BAR;

  bf16x8_t af[4][2], ag[4][2], b0[2][2], b1[2][2];
  const int NI = Kd >> 7;  // iterations of 2 K-tiles
  for (int i = 0; i < NI; ++i) {
    const int k0 = i << 7;
    const bool pf = (i + 1) < NI;

    // ---- P1: buf0 Q(0,0); stage buf1.A0 (tile 2i+1) ----
    LDA4(af, aSlotOff, 0);
    LDB2(b0, bSlotOff, lcB);
    STG(sA0, stepA, 32768, k0 + 64);
    BAR;
    LGKM0;
    MMA16(0, 0, af, b0);
    BAR;

    // ---- P2: Q(0,1); stage buf1.A1 ----
    LDB2(b1, bSlotOff, lcB + 32);
    STG(sA1, stepA, 32768 + 8192, k0 + 64);
    BAR;
    LGKM0;
    MMA16(0, 1, af, b1);
    BAR;

    // ---- P3: Q(1,0); stage buf0.B0 (tile 2i+2) ----
    LDA4(ag, aSlotOff, 64);
    if (pf) STG(sB0, stepB, 16384, k0 + 128);
    BAR;
    LGKM0;
    MMA16(1, 0, ag, b0);
    BAR;

    // ---- P4: Q(1,1); stage buf0.B1; counted vm-wait ----
    if (pf) STG(sB1, stepB, 24576, k0 + 128);
    BAR;
    MMA16(1, 1, ag, b1);
    if (pf)
      asm volatile("s_waitcnt vmcnt(4)" ::: "memory");
    else
      asm volatile("s_waitcnt vmcnt(0)" ::: "memory");
    BAR;

    // ---- P5: buf1 Q(0,0); stage buf0.A0 (tile 2i+2) ----
    LDA4(af, 32768 + aSlotOff, 0);
    LDB2(b0, 32768 + bSlotOff, lcB);
    if (pf) STG(sA0, stepA, 0, k0 + 128);
    BAR;
    LGKM0;
    MMA16(0, 0, af, b0);
    BAR;

    // ---- P6: Q(0,1); stage buf0.A1 ----
    LDB2(b1, 32768 + bSlotOff, lcB + 32);
    if (pf) STG(sA1, stepA, 8192, k0 + 128);
    BAR;
    LGKM0;
    MMA16(0, 1, af, b1);
    BAR;

    // ---- P7: Q(1,0); stage buf1.B0 (tile 2i+3) ----
    LDA4(ag, 32768 + aSlotOff, 64);
    if (pf) STG(sB0, stepB, 32768 + 16384, k0 + 192);
    BAR;
    LGKM0;
    MMA16(1, 0, ag, b0);
    BAR;

    // ---- P8: Q(1,1); stage buf1.B1; counted vm-wait ----
    if (pf) STG(sB1, stepB, 32768 + 24576, k0 + 192);
    BAR;
    MMA16(1, 1, ag, b1);
    if (pf) asm volatile("s_waitcnt vmcnt(4)" ::: "memory");
    BAR;
  }
#undef BAR
#undef LGKM0

  // Epilogue. C/D layout: col = lane&15, row = (lane>>4)*4 + reg.
  // acc[a][b] -> wave-local row a*16 (quadrant-major == linear), col b*16.
  const long cRow0 = rowA + wr * 128;
  const int cCol0 = (int)rowB + wc * 64;
#pragma unroll
  for (int a = 0; a < 8; ++a) {
#pragma unroll
    for (int b = 0; b < 4; ++b) {
      f32x4_t v4 = acc[a][b];
      const int col = cCol0 + b * 16 + fr;
#pragma unroll
      for (int r = 0; r < 4; ++r) {
        const long row = cRow0 + a * 16 + ko * 4 + r;
        float val = v4[r];
        if constexpr (EPI == 0) {
          val += bias[col];
        } else {
          val = 1.f / (1.f + __expf(-val));
        }
        C0[row * (long)ldc + col] = val;
      }
    }
  }
}

// ---------------------------------------------------------------------------
// Row LayerNorm + ReLU over h [8192 x 2048] f32; writes bf16 h' IN PLACE
// (bf16 row stride 4096 elems = the f32 row byte size). Reads before writes.
// ---------------------------------------------------------------------------
__global__ __launch_bounds__(256) void ln_relu_kernel(
    void* hptr, const float* __restrict__ ln_w, const float* __restrict__ ln_b) {
  const int H = H_DIM;
  float* h = (float*)hptr;
  __hip_bfloat16* hb = (__hip_bfloat16*)hptr;

  const long row = blockIdx.x;
  const int t = threadIdx.x;
  const int lane = t & 63;
  const int wv = t >> 6;
  const float* hr = h + row * H;

  float v[8];
#pragma unroll
  for (int i = 0; i < 8; ++i) v[i] = hr[t + i * 256];

  __shared__ float red[8];

  float s = 0.f;
#pragma unroll
  for (int i = 0; i < 8; ++i) s += v[i];
#pragma unroll
  for (int off = 32; off; off >>= 1) s += __shfl_down(s, off);
  if (lane == 0) red[wv] = s;
  __syncthreads();
  const float mu = (red[0] + red[1] + red[2] + red[3]) * (1.f / (float)H);

  float vs = 0.f;
#pragma unroll
  for (int i = 0; i < 8; ++i) {
    float d = v[i] - mu;
    vs += d * d;
  }
#pragma unroll
  for (int off = 32; off; off >>= 1) vs += __shfl_down(vs, off);
  if (lane == 0) red[4 + wv] = vs;
  __syncthreads();
  const float var = (red[4] + red[5] + red[6] + red[7]) * (1.f / (float)H);
  const float rs = rsqrtf(var + LN_EPS);

  __hip_bfloat16* hbr = hb + row * (long)D_DIM;
#pragma unroll
  for (int i = 0; i < 8; ++i) {
    int col = t + i * 256;
    float y = (v[i] - mu) * rs * ln_w[col] + ln_b[col];
    y = fmaxf(y, 0.f);
    hbr[col] = __float2bfloat16(y);
  }
}

// ---------------------------------------------------------------------------
extern "C" void kernel_launch(void* const* d_in, const int* in_sizes, int n_in,
                              void* d_out, int out_size, void* d_ws,
                              size_t ws_size, hipStream_t stream) {
  const float* x = (const float*)d_in[0];     // [8192,4096]
  const float* beta = (const float*)d_in[1];  // [4096,512]
  const float* cmean = (const float*)d_in[2]; // [4096]
  const float* W1 = (const float*)d_in[3];    // [2048,4096]
  const float* b1 = (const float*)d_in[4];    // [2048]
  const float* ln_w = (const float*)d_in[5];  // [2048]
  const float* ln_b = (const float*)d_in[6];  // [2048]
  const float* W2 = (const float*)d_in[7];    // [512,2048]
  const float* b2 = (const float*)d_in[8];    // [512]

  float* out = (float*)d_out;
  float* q0 = out;                          // [8192,512]
  float* xr = out + (size_t)B_DIM * K_DIM;  // [8192,4096] — 134 MB region
  float* q2 = xr + (size_t)B_DIM * D_DIM;   // [8192,512]
  float* q3 = q2 + (size_t)B_DIM * K_DIM;   // [8192,512]

  // Scratch inside d_out's xr region (dead until final decode GEMM):
  //   xb: bf16(x - cmean) [8192,4096] = 64 MB at xr+0
  //   h : f32 fc1 output  [8192,2048] = 64 MB at xr + 16.78M floats
  __hip_bfloat16* xb = (__hip_bfloat16*)xr;
  float* h = xr + (size_t)B_DIM * D_DIM / 2;
  __hip_bfloat16* hb = (__hip_bfloat16*)h;  // ln_relu writes bf16 in place

  // ws: bf16 weights + q bf16 (30 MB total; ws proven >= 64 MB)
  __hip_bfloat16* W1b = (__hip_bfloat16*)d_ws;          // 2048*4096
  __hip_bfloat16* W2b = W1b + (size_t)H_DIM * D_DIM;    // 512*2048
  __hip_bfloat16* betab = W2b + (size_t)K_DIM * H_DIM;  // 4096*512
  __hip_bfloat16* qb = betab + (size_t)D_DIM * K_DIM;   // 8192*512

  dim3 blk(256, 1, 1);
  dim3 blk512(512, 1, 1);

  // Pre-convert to bf16 (memory-bound, 2 launches)
  hipLaunchKernelGGL(conv_x_kernel, dim3((B_DIM * (size_t)D_DIM) / 2048), blk,
                     0, stream, x, cmean, xb);
  hipLaunchKernelGGL(conv_w3_kernel, dim3(4096 + 512 + 1024), blk, 0, stream,
                     W1, W2, beta, W1b, W2b, betab);

  // fc1: h = xb @ W1b^T + b1   [M=8192, N=2048, Kd=4096] — 8-phase 256^2
  hipLaunchKernelGGL((gemm256_8p<0>), dim3(H_DIM / 256, B_DIM / 256), blk512,
                     0, stream, xb, D_DIM, W1b, D_DIM, b1, h, H_DIM, D_DIM);

  // LayerNorm + ReLU -> bf16 h' in place (row stride 4096)
  hipLaunchKernelGGL(ln_relu_kernel, dim3(B_DIM), blk, 0, stream, (void*)h,
                     ln_w, ln_b);

  // fc2: q = h' @ W2b^T + b2   [M=8192, N=512, Kd=2048] -> q0,q2,q3 + qb bf16
  // (kept on 128^2 kernel: 256 blocks vs 64 at 256-tile)
  hipLaunchKernelGGL((gemm_bt<1>), dim3(K_DIM / 128, B_DIM / 128), blk, 0,
                     stream, hb, D_DIM, W2b, H_DIM, b2, q0, K_DIM, q2, q3, qb,
                     H_DIM);

  // decode: x_recon = sigmoid(qb @ betab^T)  [M=8192, N=4096, Kd=512] — 8-ph
  hipLaunchKernelGGL((gemm256_8p<2>), dim3(D_DIM / 256, B_DIM / 256), blk512,
                     0, stream, qb, K_DIM, betab, K_DIM, (const float*)nullptr,
                     xr, D_DIM, K_DIM);
}